// Round 4
// baseline (430.401 us; speedup 1.0000x reference)
//
#include <hip/hip_runtime.h>
#include <math.h>

// Algebraic collapse: out depends on h = X@We + be only through h@Wc and h@Wf.
//   logits[:, 0:20]  = X @ (We@Wc) + (be@Wc + bc)
//   logits[:, 20:40] = X @ (We@Wf) + (be@Wf + bf)
// K0: zero Weff, fold bias2 = be@[Wc|Wf] + [bc|bf]
// K1: Weff = We @ [Wc|Wf]   (same GEMM template, 8-way cross-block split-K, atomic)
// K2: out  = softmax-threshold(X @ Weff + bias2)   (fused epilogue)
//
// GEMM template: barrier-free K-loop. Block = 16 waves = 16 K-splits of the
// same 64 rows. Each wave double-buffers its OWN 64x16 chunk through a
// wave-private LDS slice (no __syncthreads in the loop; only per-wave
// s_waitcnt, scheduled by the compiler, hidden across 1280 fma-cycles/chunk
// at 4 waves/SIMD). B operand is wave-uniform -> s_load broadcast.

#define KD    2048
#define NROWS 16384
#define NCLS  20
#define NC2   40
#define SMARG 0.31f

// ws layout (floats)
#define WEFF_OFF 0          // [2048][40] = 81920 floats
#define BIAS_OFF 81920      // [40]

#define CHK   16            // k per staged chunk
#define XSTR  68            // LDS stride: write (16kq+rq)%32 2-way, read lane%32 2-way => free
#define WBUF  (2 * CHK * XSTR)          // per-wave double buffer = 2176 floats
#define NWAVE 16
#define HSLOT (64 * 41)                 // reduce slot [64 rows][40+1]
#define SMEM_FLOATS (NWAVE * WBUF)      // 34816 floats = 139,264 B (>= 8*HSLOT=20992)

template<int NCHUNK, int KSPB, bool FUSED, int S0>
__global__ __launch_bounds__(1024)
void gemm40(const float* __restrict__ A,
            const float* __restrict__ B0,      // cols 0..19, row stride S0
            const float* __restrict__ B1,      // cols 20..39, row stride S0
            const float* __restrict__ bias2,   // FUSED only
            float* __restrict__ outp)          // FUSED: out[.,20]; else Weff atomic
{
    __shared__ float smem[SMEM_FLOATS];
    const int tid  = threadIdx.x;
    const int lane = tid & 63;
    const int wu   = __builtin_amdgcn_readfirstlane(tid >> 6);   // wave 0..15

    const int m0  = (blockIdx.x / KSPB) * 64;
    const int kwb = (blockIdx.x % KSPB) * (NCHUNK * CHK * NWAVE) + wu * (NCHUNK * CHK);

    const int rq = lane >> 2;      // 0..15 base row
    const int kq = lane & 3;       // float4 index within 16-k chunk

    float* xw = smem + wu * WBUF;  // wave-private staging (double buffer)
    const float* ap = A + (size_t)(m0 + rq) * KD + kwb + 4 * kq;

    float acc[NC2];
    #pragma unroll
    for (int j = 0; j < NC2; ++j) acc[j] = 0.f;

    // prologue: load + stage chunk 0
    float4 st[4];
    #pragma unroll
    for (int it = 0; it < 4; ++it)
        st[it] = *(const float4*)(ap + (size_t)(16 * KD) * it);
    #pragma unroll
    for (int it = 0; it < 4; ++it)
        #pragma unroll
        for (int j = 0; j < 4; ++j)
            xw[(4 * kq + j) * XSTR + rq + 16 * it] = ((const float*)&st[it])[j];

    #pragma unroll 2
    for (int c = 0; c < NCHUNK; ++c) {
        // issue next chunk's global loads (consumed after this chunk's compute)
        if (c + 1 < NCHUNK)
            #pragma unroll
            for (int it = 0; it < 4; ++it)
                st[it] = *(const float4*)(ap + (c + 1) * CHK + (size_t)(16 * KD) * it);

        // compute chunk c from LDS; B rows via wave-uniform s_load broadcast
        const float* buf = xw + (c & 1) * (CHK * XSTR);
        const int kb = kwb + c * CHK;
        #pragma unroll
        for (int kk = 0; kk < CHK; ++kk) {
            float x = buf[kk * XSTR + lane];
            const float* w0 = B0 + (size_t)(kb + kk) * S0;
            const float* w1 = B1 + (size_t)(kb + kk) * S0;
            #pragma unroll
            for (int j = 0; j < 20; ++j) acc[j]      = fmaf(x, w0[j], acc[j]);
            #pragma unroll
            for (int j = 0; j < 20; ++j) acc[20 + j] = fmaf(x, w1[j], acc[20 + j]);
        }

        // stage next chunk into the other buffer (no barrier: wave-private)
        if (c + 1 < NCHUNK) {
            float* nb = xw + ((c + 1) & 1) * (CHK * XSTR);
            #pragma unroll
            for (int it = 0; it < 4; ++it)
                #pragma unroll
                for (int j = 0; j < 4; ++j)
                    nb[(4 * kq + j) * XSTR + rq + 16 * it] = ((const float*)&st[it])[j];
        }
    }

    // ---- cross-wave K-split reduce: 16 -> 8 -> epilogue (3 barriers total) ----
    __syncthreads();
    float* H = smem;
    if (wu >= 8) {
        float* hp = H + (wu - 8) * HSLOT + lane * 41;
        #pragma unroll
        for (int j = 0; j < NC2; ++j) hp[j] = acc[j];
    }
    __syncthreads();
    if (wu < 8) {
        float* hp = H + wu * HSLOT + lane * 41;
        #pragma unroll
        for (int j = 0; j < NC2; ++j) hp[j] += acc[j];
    }
    __syncthreads();

    if (tid < 64) {
        float l[NC2];
        #pragma unroll
        for (int j = 0; j < NC2; ++j) {
            float s = 0.f;
            #pragma unroll
            for (int ks = 0; ks < 8; ++ks) s += H[ks * HSLOT + tid * 41 + j];
            l[j] = s;
        }
        if (FUSED) {
            #pragma unroll
            for (int j = 0; j < NC2; ++j) l[j] += bias2[j];
            float mC = l[0];
            #pragma unroll
            for (int c = 1; c < NCLS; ++c) mC = fmaxf(mC, l[c]);
            float sC = 0.f;
            #pragma unroll
            for (int c = 0; c < NCLS; ++c) sC += expf(l[c] - mC);
            float mF = l[NCLS], mnF = l[NCLS];
            #pragma unroll
            for (int c = NCLS + 1; c < NC2; ++c) {
                float v = l[c];
                mF = fmaxf(mF, v);
                mnF = fminf(mnF, v);
            }
            float sF = 0.f;
            #pragma unroll
            for (int c = NCLS; c < NC2; ++c) sF += expf(l[c] - mF);
            float pred  = 1.f / sC;                 // max softmax == exp(0)/sum
            float tau   = expf(mnF - mF) / sF;      // min softmax of flow head
            float scale = (pred >= tau + SMARG) ? pred : 0.f;
            float o[NCLS];
            #pragma unroll
            for (int c = 0; c < NCLS; ++c) o[c] = expf(l[c] - mC) * scale;
            float* op = outp + (size_t)(m0 + tid) * NCLS;
            #pragma unroll
            for (int q = 0; q < 5; ++q)
                *(float4*)(op + 4 * q) = make_float4(o[4*q], o[4*q+1], o[4*q+2], o[4*q+3]);
        } else {
            float* wp = outp + (size_t)(m0 + tid) * NC2;
            #pragma unroll
            for (int j = 0; j < NC2; ++j)
                atomicAdd(wp + j, l[j]);
        }
    }
}

// ---------------- K0: zero Weff + fold bias2 --------------------------------
__global__ __launch_bounds__(1024)
void k0_prep(const float* __restrict__ be,
             const float* __restrict__ Wc, const float* __restrict__ bc,
             const float* __restrict__ Wf, const float* __restrict__ bf,
             float* __restrict__ ws)
{
    const int bid = blockIdx.x;
    const int tid = threadIdx.x;
    if (bid < 20) {                       // zero Weff: 20*1024 float4 = 81920 floats
        ((float4*)(ws + WEFF_OFF))[bid * 1024 + tid] = make_float4(0.f, 0.f, 0.f, 0.f);
        return;
    }
    // bias fold: bias2[c] = sum_k be[k]*W[k][c] + b[c]
    const int wu = tid >> 6, lane = tid & 63;
    for (int col = wu; col < NC2; col += 16) {
        const float* Wp = (col < NCLS) ? Wc : Wf;
        const int cc = (col < NCLS) ? col : col - NCLS;
        float p = 0.f;
        #pragma unroll
        for (int i = 0; i < KD / 64; ++i) {
            int k = lane + 64 * i;
            p = fmaf(be[k], Wp[k * NCLS + cc], p);
        }
        #pragma unroll
        for (int s = 32; s > 0; s >>= 1)
            p += __shfl_xor(p, s, 64);
        if (lane == 0)
            ws[BIAS_OFF + col] = p + ((col < NCLS) ? bc[cc] : bf[cc]);
    }
}

extern "C" void kernel_launch(void* const* d_in, const int* in_sizes, int n_in,
                              void* d_out, int out_size, void* d_ws, size_t ws_size,
                              hipStream_t stream) {
    const float* X  = (const float*)d_in[0];
    const float* We = (const float*)d_in[1];
    const float* be = (const float*)d_in[2];
    const float* Wc = (const float*)d_in[3];
    const float* bc = (const float*)d_in[4];
    const float* Wf = (const float*)d_in[5];
    const float* bf = (const float*)d_in[6];
    float* out = (float*)d_out;
    float* ws  = (float*)d_ws;
    (void)in_sizes; (void)n_in; (void)out_size; (void)ws_size;

    // K0: zero Weff + fold bias2
    k0_prep<<<dim3(21), dim3(1024), 0, stream>>>(be, Wc, bc, Wf, bf, ws);
    // K1: Weff = We @ [Wc|Wf]; 32 row-groups x 8 K-split blocks, 1 chunk/wave
    gemm40<1, 8, false, NCLS><<<dim3(256), dim3(1024), 0, stream>>>(
        We, Wc, Wf, nullptr, ws + WEFF_OFF);
    // K2: out = softmax-threshold(X @ Weff + bias2); 256 row-group blocks
    gemm40<8, 1, true, NC2><<<dim3(256), dim3(1024), 0, stream>>>(
        X, ws + WEFF_OFF, ws + WEFF_OFF + NCLS, ws + BIAS_OFF, out);
}

// Round 5
// 418.855 us; speedup vs baseline: 1.0276x; 1.0276x over previous
//
#include <hip/hip_runtime.h>
#include <math.h>

// Algebraic collapse: out depends on h = X@We + be only through h@Wc and h@Wf.
//   logits[:, 0:20]  = X @ (We@Wc) + (be@Wc + bc)
//   logits[:, 20:40] = X @ (We@Wf) + (be@Wf + bf)
// K0: zero Weff, fold bias2 = be@[Wc|Wf] + [bc|bf]
// K1: Weff = We @ [Wc|Wf]   (same GEMM template, 8-way cross-block split-K, atomic)
// K2: out  = softmax-threshold(X @ Weff + bias2)   (fused epilogue)
//
// GEMM template: barrier-free K-loop. Block = 16 waves = 16 K-splits of the
// same 64 rows. Each wave double-buffers its OWN 64x16 chunk through a
// wave-private LDS slice (no __syncthreads in the loop). B operand is
// wave-uniform -> scalar s_load broadcast.
//
// Round-5 fix: __launch_bounds__(1024, 4) -> 128-VGPR cap. Round 4's implicit
// 64-VGPR cap (VGPR_Count=56 = acc[40]+st[16] exactly) spilled the
// accumulators inside the kk-loop: 46 MB of scratch write-back and ~6x VALU
// inflation (211 us per gemm40). Live set is ~80 VGPRs -> fits at 4 waves/EU.

#define KD    2048
#define NROWS 16384
#define NCLS  20
#define NC2   40
#define SMARG 0.31f

// ws layout (floats)
#define WEFF_OFF 0          // [2048][40] = 81920 floats
#define BIAS_OFF 81920      // [40]

#define CHK   16            // k per staged chunk
#define XSTR  68            // LDS stride: write (rq+16kq)%32 2-way, read lane%32 2-way => free
#define WBUF  (2 * CHK * XSTR)          // per-wave double buffer = 2176 floats
#define NWAVE 16
#define HSLOT (64 * 41)                 // reduce slot [64 rows][40+1]
#define SMEM_FLOATS (NWAVE * WBUF)      // 34816 floats = 139,264 B (>= 8*HSLOT=20992)

template<int NCHUNK, int KSPB, bool FUSED, int S0>
__global__ __launch_bounds__(1024, 4)
void gemm40(const float* __restrict__ A,
            const float* __restrict__ B0,      // cols 0..19, row stride S0
            const float* __restrict__ B1,      // cols 20..39, row stride S0
            const float* __restrict__ bias2,   // FUSED only
            float* __restrict__ outp)          // FUSED: out[.,20]; else Weff atomic
{
    __shared__ float smem[SMEM_FLOATS];
    const int tid  = threadIdx.x;
    const int lane = tid & 63;
    const int wu   = __builtin_amdgcn_readfirstlane(tid >> 6);   // wave 0..15

    const int m0  = (blockIdx.x / KSPB) * 64;
    const int kwb = (blockIdx.x % KSPB) * (NCHUNK * CHK * NWAVE) + wu * (NCHUNK * CHK);

    const int rq = lane >> 2;      // 0..15 base row
    const int kq = lane & 3;       // float4 index within 16-k chunk

    float* xw = smem + wu * WBUF;  // wave-private staging (double buffer)
    const float* ap = A + (size_t)(m0 + rq) * KD + kwb + 4 * kq;

    float acc[NC2];
    #pragma unroll
    for (int j = 0; j < NC2; ++j) acc[j] = 0.f;

    // prologue: load + stage chunk 0
    float4 st[4];
    #pragma unroll
    for (int it = 0; it < 4; ++it)
        st[it] = *(const float4*)(ap + (size_t)(16 * KD) * it);
    #pragma unroll
    for (int it = 0; it < 4; ++it)
        #pragma unroll
        for (int j = 0; j < 4; ++j)
            xw[(4 * kq + j) * XSTR + rq + 16 * it] = ((const float*)&st[it])[j];

    for (int c = 0; c < NCHUNK; ++c) {
        // issue next chunk's global loads (consumed after this chunk's compute)
        if (c + 1 < NCHUNK)
            #pragma unroll
            for (int it = 0; it < 4; ++it)
                st[it] = *(const float4*)(ap + (c + 1) * CHK + (size_t)(16 * KD) * it);

        // compute chunk c from LDS; B rows via wave-uniform s_load broadcast
        const float* buf = xw + (c & 1) * (CHK * XSTR);
        const int kb = kwb + c * CHK;
        #pragma unroll
        for (int kk = 0; kk < CHK; ++kk) {
            float x = buf[kk * XSTR + lane];
            const float* w0 = B0 + (size_t)(kb + kk) * S0;
            const float* w1 = B1 + (size_t)(kb + kk) * S0;
            #pragma unroll
            for (int j = 0; j < 20; ++j) acc[j]      = fmaf(x, w0[j], acc[j]);
            #pragma unroll
            for (int j = 0; j < 20; ++j) acc[20 + j] = fmaf(x, w1[j], acc[20 + j]);
        }

        // stage next chunk into the other buffer (no barrier: wave-private)
        if (c + 1 < NCHUNK) {
            float* nb = xw + ((c + 1) & 1) * (CHK * XSTR);
            #pragma unroll
            for (int it = 0; it < 4; ++it)
                #pragma unroll
                for (int j = 0; j < 4; ++j)
                    nb[(4 * kq + j) * XSTR + rq + 16 * it] = ((const float*)&st[it])[j];
        }
    }

    // ---- cross-wave K-split reduce: 16 -> 8 -> epilogue (3 barriers total) ----
    __syncthreads();
    float* H = smem;
    if (wu >= 8) {
        float* hp = H + (wu - 8) * HSLOT + lane * 41;
        #pragma unroll
        for (int j = 0; j < NC2; ++j) hp[j] = acc[j];
    }
    __syncthreads();
    if (wu < 8) {
        float* hp = H + wu * HSLOT + lane * 41;
        #pragma unroll
        for (int j = 0; j < NC2; ++j) hp[j] += acc[j];
    }
    __syncthreads();

    if (tid < 64) {
        float l[NC2];
        #pragma unroll
        for (int j = 0; j < NC2; ++j) {
            float s = 0.f;
            #pragma unroll
            for (int ks = 0; ks < 8; ++ks) s += H[ks * HSLOT + tid * 41 + j];
            l[j] = s;
        }
        if (FUSED) {
            #pragma unroll
            for (int j = 0; j < NC2; ++j) l[j] += bias2[j];
            float mC = l[0];
            #pragma unroll
            for (int c = 1; c < NCLS; ++c) mC = fmaxf(mC, l[c]);
            float sC = 0.f;
            #pragma unroll
            for (int c = 0; c < NCLS; ++c) sC += expf(l[c] - mC);
            float mF = l[NCLS], mnF = l[NCLS];
            #pragma unroll
            for (int c = NCLS + 1; c < NC2; ++c) {
                float v = l[c];
                mF = fmaxf(mF, v);
                mnF = fminf(mnF, v);
            }
            float sF = 0.f;
            #pragma unroll
            for (int c = NCLS; c < NC2; ++c) sF += expf(l[c] - mF);
            float pred  = 1.f / sC;                 // max softmax == exp(0)/sum
            float tau   = expf(mnF - mF) / sF;      // min softmax of flow head
            float scale = (pred >= tau + SMARG) ? pred : 0.f;
            float o[NCLS];
            #pragma unroll
            for (int c = 0; c < NCLS; ++c) o[c] = expf(l[c] - mC) * scale;
            float* op = outp + (size_t)(m0 + tid) * NCLS;
            #pragma unroll
            for (int q = 0; q < 5; ++q)
                *(float4*)(op + 4 * q) = make_float4(o[4*q], o[4*q+1], o[4*q+2], o[4*q+3]);
        } else {
            float* wp = outp + (size_t)(m0 + tid) * NC2;
            #pragma unroll
            for (int j = 0; j < NC2; ++j)
                atomicAdd(wp + j, l[j]);
        }
    }
}

// ---------------- K0: zero Weff + fold bias2 --------------------------------
__global__ __launch_bounds__(1024)
void k0_prep(const float* __restrict__ be,
             const float* __restrict__ Wc, const float* __restrict__ bc,
             const float* __restrict__ Wf, const float* __restrict__ bf,
             float* __restrict__ ws)
{
    const int bid = blockIdx.x;
    const int tid = threadIdx.x;
    if (bid < 20) {                       // zero Weff: 20*1024 float4 = 81920 floats
        ((float4*)(ws + WEFF_OFF))[bid * 1024 + tid] = make_float4(0.f, 0.f, 0.f, 0.f);
        return;
    }
    // bias fold: bias2[c] = sum_k be[k]*W[k][c] + b[c]
    const int wu = tid >> 6, lane = tid & 63;
    for (int col = wu; col < NC2; col += 16) {
        const float* Wp = (col < NCLS) ? Wc : Wf;
        const int cc = (col < NCLS) ? col : col - NCLS;
        float p = 0.f;
        #pragma unroll
        for (int i = 0; i < KD / 64; ++i) {
            int k = lane + 64 * i;
            p = fmaf(be[k], Wp[k * NCLS + cc], p);
        }
        #pragma unroll
        for (int s = 32; s > 0; s >>= 1)
            p += __shfl_xor(p, s, 64);
        if (lane == 0)
            ws[BIAS_OFF + col] = p + ((col < NCLS) ? bc[cc] : bf[cc]);
    }
}

extern "C" void kernel_launch(void* const* d_in, const int* in_sizes, int n_in,
                              void* d_out, int out_size, void* d_ws, size_t ws_size,
                              hipStream_t stream) {
    const float* X  = (const float*)d_in[0];
    const float* We = (const float*)d_in[1];
    const float* be = (const float*)d_in[2];
    const float* Wc = (const float*)d_in[3];
    const float* bc = (const float*)d_in[4];
    const float* Wf = (const float*)d_in[5];
    const float* bf = (const float*)d_in[6];
    float* out = (float*)d_out;
    float* ws  = (float*)d_ws;
    (void)in_sizes; (void)n_in; (void)out_size; (void)ws_size;

    // K0: zero Weff + fold bias2
    k0_prep<<<dim3(21), dim3(1024), 0, stream>>>(be, Wc, bc, Wf, bf, ws);
    // K1: Weff = We @ [Wc|Wf]; 32 row-groups x 8 K-split blocks, 1 chunk/wave
    gemm40<1, 8, false, NCLS><<<dim3(256), dim3(1024), 0, stream>>>(
        We, Wc, Wf, nullptr, ws + WEFF_OFF);
    // K2: out = softmax-threshold(X @ Weff + bias2); 256 row-group blocks
    gemm40<8, 1, true, NC2><<<dim3(256), dim3(1024), 0, stream>>>(
        X, ws + WEFF_OFF, ws + WEFF_OFF + NCLS, ws + BIAS_OFF, out);
}

// Round 6
// 316.203 us; speedup vs baseline: 1.3612x; 1.3246x over previous
//
#include <hip/hip_runtime.h>
#include <math.h>

// Algebraic collapse: out depends on h = X@We + be only through h@Wc and h@Wf.
//   logits[:, 0:20]  = X @ (We@Wc) + (be@Wc + bc)
//   logits[:, 20:40] = X @ (We@Wf) + (be@Wf + bf)
// K0: zero Weff, fold bias2 = be@[Wc|Wf] + [bc|bf]
// K1: Weff = We @ [Wc|Wf]   (gemm40 template, 8-way cross-block split-K, atomic)
// K2: out  = softmax-threshold(X @ Weff + bias2)   (fused epilogue)
//
// Round-6: kill the register spill by construction. Rounds 4/5 proved the
// allocator caps arch-VGPRs at ~64 regardless of __launch_bounds__ hints
// (VGPR_Count 56/52, spill movs -> 6x VALU inflation, 200 us/gemm40).
// Live set is now <= ~56: acc[40] + one float4 + addressing. The 16 staging
// VGPRs are eliminated via __builtin_amdgcn_global_load_lds (direct-to-LDS
// DMA, width 16), wave-private double buffer, manual s_waitcnt vmcnt(N)
// pipelining -- no __syncthreads in the K-loop.
//
// LDS granule swizzle (global_load_lds forces dest = base + lane*16B):
// granule (row r, k-group q) at granule-index p = 4r + ((q + (r>>2)) & 3).
// Per DMA instruction 'it' (16 rows), p = 64*it + lane is contiguous [ok for
// the DMA]; lane's global src = row 16it+(lane>>2), k-group ((lane&3)-(lane>>4))&3.
// Read side: lane = row, ds_read_b128 at float-offset 16*lane + 4*((q+(lane>>2))&3)
// -> 64 lanes spread over 8 bank-groups (8-way, ~2.94x on 4 reads/chunk = ~140
// cyc, hidden under 1280 FMA cyc/chunk).

#define KD    2048
#define NROWS 16384
#define NCLS  20
#define NC2   40
#define SMARG 0.31f

// ws layout (floats)
#define WEFF_OFF 0          // [2048][40] = 81920 floats
#define BIAS_OFF 81920      // [40]

#define CHK   16            // k per staged chunk
#define NWAVE 16
#define WBUF  2048          // floats per wave: 2 buffers x 1024 (64 rows x 16 k)
#define HSLOT (64 * 41)     // reduce slot [64 rows][40+1]
#define SMEM_FLOATS (NWAVE * WBUF)   // 32768 floats = 131072 B (>= 8*HSLOT = 20992)

#define WAITVM4() asm volatile("s_waitcnt vmcnt(4)" ::: "memory")
#define WAITVM0() asm volatile("s_waitcnt vmcnt(0)" ::: "memory")

__device__ __forceinline__ void gload_lds16(const float* g, float* l) {
    __builtin_amdgcn_global_load_lds(
        (const __attribute__((address_space(1))) unsigned int*)g,
        (__attribute__((address_space(3))) unsigned int*)l, 16, 0, 0);
}

template<int NCHUNK, int KSPB, bool FUSED, int S0>
__global__ __launch_bounds__(1024)
void gemm40(const float* __restrict__ A,
            const float* __restrict__ B0,      // cols 0..19, row stride S0
            const float* __restrict__ B1,      // cols 20..39, row stride S0
            const float* __restrict__ bias2,   // FUSED only
            float* __restrict__ outp)          // FUSED: out[.,20]; else Weff atomic
{
    __shared__ float smem[SMEM_FLOATS];
    const int tid  = threadIdx.x;
    const int lane = tid & 63;
    const int wu   = __builtin_amdgcn_readfirstlane(tid >> 6);   // wave 0..15

    const int m0  = (blockIdx.x / KSPB) * 64;
    const int kwb = (blockIdx.x % KSPB) * (NCHUNK * CHK * NWAVE) + wu * (NCHUNK * CHK);

    float* xw = smem + wu * WBUF;              // wave-private double buffer

    // DMA write-side lane map (it-independent parts)
    const int q_w  = ((lane & 3) - (lane >> 4)) & 3;   // k-group this lane fetches
    const int rsub = lane >> 2;                        // row-within-instruction
    const float* g0 = A + (size_t)(m0 + rsub) * KD + kwb + 4 * q_w;

    float acc[NC2];
    #pragma unroll
    for (int j = 0; j < NC2; ++j) acc[j] = 0.f;

    // prologue: issue chunk 0 into buffer 0 (4 DMA instrs, 16 rows each)
    #pragma unroll
    for (int it = 0; it < 4; ++it)
        gload_lds16(g0 + (size_t)(16 * KD) * it, xw + it * 256);

    #pragma unroll 1
    for (int c = 0; c < NCHUNK; ++c) {
        const int buf = c & 1;
        if (c + 1 < NCHUNK) {
            #pragma unroll
            for (int it = 0; it < 4; ++it)
                gload_lds16(g0 + (c + 1) * CHK + (size_t)(16 * KD) * it,
                            xw + (buf ^ 1) * 1024 + it * 256);
            WAITVM4();                         // chunk c's 4 DMAs (oldest) done
        } else {
            WAITVM0();
        }
        const float* bufp = xw + buf * 1024;
        const int kb = kwb + c * CHK;
        #pragma unroll
        for (int q = 0; q < 4; ++q) {
            const int s = (q + (lane >> 2)) & 3;
            const float4 x4 = *(const float4*)(bufp + 16 * lane + 4 * s);
            #pragma unroll
            for (int j2 = 0; j2 < 4; ++j2) {
                const float xv = ((const float*)&x4)[j2];
                const float* w0 = B0 + (size_t)(kb + 4 * q + j2) * S0;  // uniform -> s_load
                const float* w1 = B1 + (size_t)(kb + 4 * q + j2) * S0;
                #pragma unroll
                for (int j = 0; j < 20; ++j) acc[j]      = fmaf(xv, w0[j], acc[j]);
                #pragma unroll
                for (int j = 0; j < 20; ++j) acc[20 + j] = fmaf(xv, w1[j], acc[20 + j]);
            }
        }
    }

    // ---- cross-wave K-split reduce: 16 -> 8 -> epilogue ----
    __syncthreads();
    float* H = smem;
    if (wu >= 8) {
        float* hp = H + (wu - 8) * HSLOT + lane * 41;
        #pragma unroll
        for (int j = 0; j < NC2; ++j) hp[j] = acc[j];
    }
    __syncthreads();
    if (wu < 8) {
        float* hp = H + wu * HSLOT + lane * 41;
        #pragma unroll
        for (int j = 0; j < NC2; ++j) hp[j] += acc[j];
    }
    __syncthreads();

    if (tid < 64) {
        float l[NC2];
        #pragma unroll
        for (int j = 0; j < NC2; ++j) {
            float sv = 0.f;
            #pragma unroll
            for (int ks = 0; ks < 8; ++ks) sv += H[ks * HSLOT + tid * 41 + j];
            l[j] = sv;
        }
        if (FUSED) {
            #pragma unroll
            for (int j = 0; j < NC2; ++j) l[j] += bias2[j];
            float mC = l[0];
            #pragma unroll
            for (int c = 1; c < NCLS; ++c) mC = fmaxf(mC, l[c]);
            float sC = 0.f;
            #pragma unroll
            for (int c = 0; c < NCLS; ++c) sC += expf(l[c] - mC);
            float mF = l[NCLS], mnF = l[NCLS];
            #pragma unroll
            for (int c = NCLS + 1; c < NC2; ++c) {
                float v = l[c];
                mF = fmaxf(mF, v);
                mnF = fminf(mnF, v);
            }
            float sF = 0.f;
            #pragma unroll
            for (int c = NCLS; c < NC2; ++c) sF += expf(l[c] - mF);
            float pred  = 1.f / sC;                 // max softmax == exp(0)/sum
            float tau   = expf(mnF - mF) / sF;      // min softmax of flow head
            float scale = (pred >= tau + SMARG) ? pred : 0.f;
            float o[NCLS];
            #pragma unroll
            for (int c = 0; c < NCLS; ++c) o[c] = expf(l[c] - mC) * scale;
            float* op = outp + (size_t)(m0 + tid) * NCLS;
            #pragma unroll
            for (int qq = 0; qq < 5; ++qq)
                *(float4*)(op + 4 * qq) =
                    make_float4(o[4*qq], o[4*qq+1], o[4*qq+2], o[4*qq+3]);
        } else {
            float* wp = outp + (size_t)(m0 + tid) * NC2;
            #pragma unroll
            for (int j = 0; j < NC2; ++j)
                atomicAdd(wp + j, l[j]);
        }
    }
}

// ---------------- K0: zero Weff + fold bias2 --------------------------------
__global__ __launch_bounds__(1024)
void k0_prep(const float* __restrict__ be,
             const float* __restrict__ Wc, const float* __restrict__ bc,
             const float* __restrict__ Wf, const float* __restrict__ bf,
             float* __restrict__ ws)
{
    const int bid = blockIdx.x;
    const int tid = threadIdx.x;
    if (bid < 20) {                       // zero Weff: 20*1024 float4 = 81920 floats
        ((float4*)(ws + WEFF_OFF))[bid * 1024 + tid] = make_float4(0.f, 0.f, 0.f, 0.f);
        return;
    }
    // bias fold: bias2[c] = sum_k be[k]*W[k][c] + b[c]
    const int wu = tid >> 6, lane = tid & 63;
    for (int col = wu; col < NC2; col += 16) {
        const float* Wp = (col < NCLS) ? Wc : Wf;
        const int cc = (col < NCLS) ? col : col - NCLS;
        float p = 0.f;
        #pragma unroll
        for (int i = 0; i < KD / 64; ++i) {
            int k = lane + 64 * i;
            p = fmaf(be[k], Wp[k * NCLS + cc], p);
        }
        #pragma unroll
        for (int s = 32; s > 0; s >>= 1)
            p += __shfl_xor(p, s, 64);
        if (lane == 0)
            ws[BIAS_OFF + col] = p + ((col < NCLS) ? bc[cc] : bf[cc]);
    }
}

extern "C" void kernel_launch(void* const* d_in, const int* in_sizes, int n_in,
                              void* d_out, int out_size, void* d_ws, size_t ws_size,
                              hipStream_t stream) {
    const float* X  = (const float*)d_in[0];
    const float* We = (const float*)d_in[1];
    const float* be = (const float*)d_in[2];
    const float* Wc = (const float*)d_in[3];
    const float* bc = (const float*)d_in[4];
    const float* Wf = (const float*)d_in[5];
    const float* bf = (const float*)d_in[6];
    float* out = (float*)d_out;
    float* ws  = (float*)d_ws;
    (void)in_sizes; (void)n_in; (void)out_size; (void)ws_size;

    // K0: zero Weff + fold bias2
    k0_prep<<<dim3(21), dim3(1024), 0, stream>>>(be, Wc, bc, Wf, bf, ws);
    // K1: Weff = We @ [Wc|Wf]; 32 row-groups x 8 K-split blocks, 1 chunk/wave
    gemm40<1, 8, false, NCLS><<<dim3(256), dim3(1024), 0, stream>>>(
        We, Wc, Wf, nullptr, ws + WEFF_OFF);
    // K2: out = softmax-threshold(X @ Weff + bias2); 256 row-group blocks
    gemm40<8, 1, true, NC2><<<dim3(256), dim3(1024), 0, stream>>>(
        X, ws + WEFF_OFF, ws + WEFF_OFF + NCLS, ws + BIAS_OFF, out);
}